// Round 7
// baseline (233.707 us; speedup 1.0000x reference)
//
#include <hip/hip_runtime.h>
#include <hip/hip_bf16.h>

// MHA: B=2, T=2048, D=1024, H=16, Hd=64. fp32 in/out, bf16 MFMA internally.
// R7: split-K flash (partials additive since no-max softmax), combine fused
// into out_gemm staging; X-precast dropped (proj converts fp32 in staging).

typedef __bf16 bf16_t;
typedef __bf16 bf16x8 __attribute__((ext_vector_type(8)));
typedef __bf16 bf16x4 __attribute__((ext_vector_type(4)));
typedef __bf16 bf16x2 __attribute__((ext_vector_type(2)));
typedef short short4v __attribute__((ext_vector_type(4)));
typedef float f32x4 __attribute__((ext_vector_type(4)));
typedef unsigned int u32;

#define D_MODEL 1024
#define SEQ_T   2048
#define NHEAD   16
#define HDIM    64
#define M_ROWS  4096   // B*T
#define MEGA    (1024 * 1024)

// async global->LDS, 16B per lane; LDS dest MUST be wave-uniform base + lane*16
__device__ __forceinline__ void gl2lds16(const void* g, void* l) {
    __builtin_amdgcn_global_load_lds((const __attribute__((address_space(1))) u32*)g,
                                     (__attribute__((address_space(3))) u32*)l, 16, 0, 0);
}

__device__ __forceinline__ short4v as_s4(bf16x4 v) {
    union { bf16x4 h; short4v s; } u; u.h = v; return u.s;
}

// ---------------------------------------------------------------------------
// prep: weights only. 64x64 transpose-cast tiles (W[k][n] fp32 -> Wt[n][k] bf16).
// ---------------------------------------------------------------------------
__global__ __launch_bounds__(256) void prep(
    const float* __restrict__ Wq, const float* __restrict__ Wk,
    const float* __restrict__ Wv, const float* __restrict__ Wo,
    bf16_t* __restrict__ Wqt, bf16_t* __restrict__ Wkt,
    bf16_t* __restrict__ Wvt, bf16_t* __restrict__ Wot)
{
    int blk = blockIdx.x, tid = threadIdx.x;
    int wi = blk >> 8, t = blk & 255;
    int n0 = (t & 15) * 64, k0 = (t >> 4) * 64;
    const float* W = wi == 0 ? Wq : (wi == 1 ? Wk : (wi == 2 ? Wv : Wo));
    bf16_t* Wt = wi == 0 ? Wqt : (wi == 1 ? Wkt : (wi == 2 ? Wvt : Wot));
    __shared__ float tile[64][65];
    int tx = tid & 63, ty = tid >> 6;   // 64 x 4
#pragma unroll
    for (int i = 0; i < 64; i += 4)
        tile[ty + i][tx] = W[(k0 + ty + i) * D_MODEL + n0 + tx];
    __syncthreads();
#pragma unroll
    for (int i = 0; i < 64; i += 4)
        Wt[(size_t)(n0 + ty + i) * D_MODEL + k0 + tx] = (bf16_t)tile[tx][ty + i];
}

// ---------------------------------------------------------------------------
// Fused projection GEMM (Q,K,V): 128x128 tile, BK=32, single-buffered,
// 4-chunk XOR-rotated LDS. A staged from fp32 X with in-register cvt;
// B (bf16 Wt) via global_load_lds. Q epilogue pre-scales by 0.125.
// blockIdx.y: [0..7]=Q, [8..15]=K, [16..23]=V (V writes V^T [B,H,Hd,T]).
// ---------------------------------------------------------------------------
__global__ __launch_bounds__(256) void proj_fused(
    const float* __restrict__ Xq, const float* __restrict__ Xk, const float* __restrict__ Xv,
    const bf16_t* __restrict__ Wqt, const bf16_t* __restrict__ Wkt, const bf16_t* __restrict__ Wvt,
    const float* __restrict__ bq, const float* __restrict__ bk, const float* __restrict__ bv,
    bf16_t* __restrict__ Qh, bf16_t* __restrict__ Kh, bf16_t* __restrict__ Vt)
{
    __shared__ bf16_t Ab[128 * 32];   // 8KB, [row][4 chunks rotated by row]
    __shared__ bf16_t Bb[128 * 32];   // 8KB
    int tid = threadIdx.x;
    int w = tid >> 6, lane = tid & 63, lo16 = lane & 15, quad = lane >> 4;
    int m0 = blockIdx.x * 128;
    int proj = blockIdx.y >> 3;
    int n0 = (blockIdx.y & 7) * 128;
    const float*  X    = proj == 0 ? Xq  : (proj == 1 ? Xk  : Xv);
    const bf16_t* Wt   = proj == 0 ? Wqt : (proj == 1 ? Wkt : Wvt);
    const float*  bias = proj == 0 ? bq  : (proj == 1 ? bk  : bv);
    int wm = (w >> 1) * 64, wn = (w & 1) * 64;

    f32x4 acc[4][4];
#pragma unroll
    for (int i = 0; i < 4; i++)
#pragma unroll
        for (int j = 0; j < 4; j++) acc[i][j] = (f32x4){0.f, 0.f, 0.f, 0.f};

    for (int k0 = 0; k0 < D_MODEL; k0 += 32) {
        __syncthreads();
#pragma unroll
        for (int p = 0; p < 2; p++) {
            int idx = p * 256 + tid;            // 0..511 chunks of 16B
            int row = idx >> 2, cp = idx & 3, cl = (cp - row) & 3;
            const float* as = X + (size_t)(m0 + row) * D_MODEL + k0 + cl * 8;
            float4 a0 = *(const float4*)as, a1 = *(const float4*)(as + 4);
            bf16x8 av;
            av[0] = (bf16_t)a0.x; av[1] = (bf16_t)a0.y; av[2] = (bf16_t)a0.z; av[3] = (bf16_t)a0.w;
            av[4] = (bf16_t)a1.x; av[5] = (bf16_t)a1.y; av[6] = (bf16_t)a1.z; av[7] = (bf16_t)a1.w;
            *(bf16x8*)(Ab + idx * 8) = av;
            gl2lds16(Wt + (size_t)(n0 + row) * D_MODEL + k0 + cl * 8, Bb + idx * 8);
        }
        __syncthreads();
        bf16x8 af[4], bfr[4];
#pragma unroll
        for (int i = 0; i < 4; i++) {
            int row = wm + i * 16 + lo16;
            af[i] = *(bf16x8*)(Ab + row * 32 + ((quad + row) & 3) * 8);
        }
#pragma unroll
        for (int j = 0; j < 4; j++) {
            int row = wn + j * 16 + lo16;
            bfr[j] = *(bf16x8*)(Bb + row * 32 + ((quad + row) & 3) * 8);
        }
#pragma unroll
        for (int i = 0; i < 4; i++)
#pragma unroll
            for (int j = 0; j < 4; j++)
                acc[i][j] = __builtin_amdgcn_mfma_f32_16x16x32_bf16(af[i], bfr[j], acc[i][j], 0, 0, 0);
    }

    float qscale = proj == 0 ? 0.125f : 1.0f;
#pragma unroll
    for (int j = 0; j < 4; j++) {
        int col = n0 + wn + j * 16 + lo16;
        float bv2 = bias[col];
        int h = col >> 6, hd = col & 63;
#pragma unroll
        for (int i = 0; i < 4; i++) {
#pragma unroll
            for (int r = 0; r < 4; r++) {
                int m = m0 + wm + i * 16 + quad * 4 + r;
                int b = m >> 11, t = m & 2047;
                bf16_t val = (bf16_t)((acc[i][j][r] + bv2) * qscale);
                if (proj == 2)
                    Vt[(((size_t)(b * NHEAD + h) * HDIM + hd) * SEQ_T) + t] = val;
                else if (proj == 1)
                    Kh[(((size_t)(b * NHEAD + h) * SEQ_T + t) * HDIM) + hd] = val;
                else
                    Qh[(((size_t)(b * NHEAD + h) * SEQ_T + t) * HDIM) + hd] = val;
            }
        }
    }
}

// ---------------------------------------------------------------------------
// Flash attention v7: SPLIT-K. No-max softmax makes partials additive, so
// block (bh, qt, half) computes O_partial = sum P.V and l_partial = sum P
// over its half of the key range and writes them raw; out_gemm combines.
// Grid 2048 blocks (32 qt x 2 halves x 32 bh, big-qt first) of 4 waves ->
// 5 resident blocks/CU + refill queue (20 waves/CU). S^T = K*Q^T keeps P in
// registers. K/V double-buffered. Same-bh blocks map to the same XCD.
// ---------------------------------------------------------------------------
__global__ __launch_bounds__(256) void flash_attn(const bf16_t* __restrict__ Qh,
                                                  const bf16_t* __restrict__ Kh,
                                                  const bf16_t* __restrict__ Vt,
                                                  bf16_t* __restrict__ Op0,
                                                  bf16_t* __restrict__ Op1,
                                                  float* __restrict__ L0,
                                                  float* __restrict__ L1) {
    int bi = blockIdx.x;
    int qt = 31 - (bi >> 6);           // big q-tiles dispatched first
    int half = (bi >> 5) & 1;
    int bh = bi & 31;                  // b*16 + h (fastest -> same-XCD sharing)
    int tid = threadIdx.x;
    int w = tid >> 6, lane = tid & 63, lo16 = lane & 15, quad = lane >> 4;

    __shared__ bf16_t KL[2][64 * 64];  // [key][chunk-rotated d]
    __shared__ bf16_t VL[2][64 * 64];  // [d][chunk-rotated key]

    const bf16_t* Qp = Qh + (size_t)bh * SEQ_T * HDIM;
    const bf16_t* Kp = Kh + (size_t)bh * SEQ_T * HDIM;
    const bf16_t* Vp = Vt + (size_t)bh * HDIM * SEQ_T;
    int b = bh >> 4, h = bh & 15;

    bf16_t* Op = half ? Op1 : Op0;
    float*  L  = half ? L1 : L0;

    int nt = qt + 1;
    int mid = (nt + 1) >> 1;
    int kt0 = half ? mid : 0;
    int kt1 = half ? nt  : mid;        // half1 empty iff qt==0 -> writes zeros

    int qbase = qt * 64 + w * 16;
    int qrow = qbase + lo16;

    const bf16_t* qr = Qp + (size_t)qrow * HDIM;
    bf16x8 qf0 = *(const bf16x8*)(qr + quad * 8);
    bf16x8 qf1 = *(const bf16x8*)(qr + 32 + quad * 8);

    f32x4 oacc[4];
#pragma unroll
    for (int t = 0; t < 4; t++) oacc[t] = (f32x4){0.f, 0.f, 0.f, 0.f};
    float lsum = 0.f;

    auto stageKV = [&](int buf, int kt) {
#pragma unroll
        for (int p = 0; p < 2; p++) {
            int idx = p * 256 + tid;         // 512 chunks of 16B each buf
            int row = idx >> 3, cp = idx & 7, cl = (cp - row) & 7;
            gl2lds16(Kp + (size_t)(kt * 64 + row) * HDIM + cl * 8, KL[buf] + idx * 8);
            gl2lds16(Vp + (size_t)row * SEQ_T + kt * 64 + cl * 8, VL[buf] + idx * 8);
        }
    };

    if (kt0 < kt1) {
        stageKV(0, kt0);
        __syncthreads();
        for (int j = kt0; j < kt1; j++) {
            int cur = (j - kt0) & 1;
            if (j + 1 < kt1) stageKV(cur ^ 1, j + 1);

            // K frags (A-operand of S^T)
            bf16x8 kf[4][2];
#pragma unroll
            for (int s = 0; s < 4; s++) {
                int keyr = s * 16 + lo16;
                kf[s][0] = *(bf16x8*)(KL[cur] + keyr * 64 + ((quad + keyr) & 7) * 8);
                kf[s][1] = *(bf16x8*)(KL[cur] + keyr * 64 + ((quad + 4 + keyr) & 7) * 8);
            }

            // S^T = K * Q^T -> C-layout: col=q (lane&15), row=key (quad*4+r)
            f32x4 sacc[4];
#pragma unroll
            for (int s = 0; s < 4; s++) sacc[s] = (f32x4){0.f, 0.f, 0.f, 0.f};
#pragma unroll
            for (int s = 0; s < 4; s++) {
                sacc[s] = __builtin_amdgcn_mfma_f32_16x16x32_bf16(kf[s][0], qf0, sacc[s], 0, 0, 0);
                sacc[s] = __builtin_amdgcn_mfma_f32_16x16x32_bf16(kf[s][1], qf1, sacc[s], 0, 0, 0);
            }

            bool diag = (j == qt);
            short4v pf[4];
#pragma unroll
            for (int s = 0; s < 4; s++) {
                bf16x4 pv;
#pragma unroll
                for (int r = 0; r < 4; r++) {
                    float e = __expf(sacc[s][r]);
                    if (diag) {
                        int key = j * 64 + s * 16 + quad * 4 + r;
                        e = (key <= qrow) ? e : 0.f;
                    }
                    lsum += e;
                    pv[r] = (bf16_t)e;
                }
                pf[s] = as_s4(pv);
            }

            // O^T += V^T * P^T  (A = V frag from LDS, B = register P)
#pragma unroll
            for (int t = 0; t < 4; t++) {
                int drow = t * 16 + lo16;
#pragma unroll
                for (int s = 0; s < 4; s++) {
                    int c = s * 16 + quad * 4;
                    int phys = ((c >> 3) + drow) & 7;
                    bf16x4 vf = *(bf16x4*)(VL[cur] + drow * 64 + phys * 8 + (c & 7));
                    oacc[t] = __builtin_amdgcn_mfma_f32_16x16x16bf16_1k(as_s4(vf), pf[s], oacc[t], 0, 0, 0);
                }
            }

            __syncthreads();   // guards buffer reuse (prefetch already in flight)
        }
    }

    // epilogue: write RAW partials (no normalization)
    float lt = lsum;
    lt += __shfl_xor(lt, 16);
    lt += __shfl_xor(lt, 32);
    bf16_t* dst = Op + ((size_t)b * SEQ_T + qrow) * D_MODEL + h * HDIM;
#pragma unroll
    for (int t = 0; t < 4; t++) {
#pragma unroll
        for (int rp = 0; rp < 2; rp++) {
            int d0 = t * 16 + quad * 4 + rp * 2;
            bf16x2 pk;
            pk[0] = (bf16_t)oacc[t][rp * 2];
            pk[1] = (bf16_t)oacc[t][rp * 2 + 1];
            *(bf16x2*)(dst + d0) = pk;
        }
    }
    if (quad == 0)
        L[((size_t)b * SEQ_T + qrow) * NHEAD + h] = lt;
}

// ---------------------------------------------------------------------------
// Output GEMM + split-K combine: A = (Op0+Op1)/(l0+l1) computed during
// staging, then out(fp32) = A @ Wot^T + bo. 64x128 tile, BK=32, rotated LDS.
// Grid (64,8)=512 blocks = 2/CU.
// ---------------------------------------------------------------------------
__global__ __launch_bounds__(256) void out_gemm(const bf16_t* __restrict__ Op0,
                                                const bf16_t* __restrict__ Op1,
                                                const float* __restrict__ L0,
                                                const float* __restrict__ L1,
                                                const bf16_t* __restrict__ Wt,
                                                const float* __restrict__ bias,
                                                float* __restrict__ out) {
    __shared__ bf16_t Ab[64 * 32];    // 4KB
    __shared__ bf16_t Bb[128 * 32];   // 8KB
    int tid = threadIdx.x;
    int w = tid >> 6, lane = tid & 63, lo16 = lane & 15, quad = lane >> 4;
    int m0 = blockIdx.x * 64;
    int n0 = blockIdx.y * 128;
    int wm = (w >> 1) * 32, wn = (w & 1) * 64;

    f32x4 acc[2][4];
#pragma unroll
    for (int i = 0; i < 2; i++)
#pragma unroll
        for (int j = 0; j < 4; j++) acc[i][j] = (f32x4){0.f, 0.f, 0.f, 0.f};

    for (int k0 = 0; k0 < D_MODEL; k0 += 32) {
        __syncthreads();
        {
            int idx = tid;                      // 256 chunks for A (64x32)
            int row = idx >> 2, cp = idx & 3, cl = (cp - row) & 3;
            int gr = m0 + row;
            int c0 = k0 + cl * 8;               // stays within one head block
            int hidx = gr * NHEAD + (c0 >> 6);
            float inv = 1.f / (L0[hidx] + L1[hidx]);
            bf16x8 a0 = *(const bf16x8*)(Op0 + (size_t)gr * D_MODEL + c0);
            bf16x8 a1 = *(const bf16x8*)(Op1 + (size_t)gr * D_MODEL + c0);
            bf16x8 av;
#pragma unroll
            for (int e = 0; e < 8; e++)
                av[e] = (bf16_t)(((float)a0[e] + (float)a1[e]) * inv);
            *(bf16x8*)(Ab + idx * 8) = av;
        }
#pragma unroll
        for (int p = 0; p < 2; p++) {
            int idx = p * 256 + tid;            // 512 chunks for B (128x32)
            int row = idx >> 2, cp = idx & 3, cl = (cp - row) & 3;
            gl2lds16(Wt + (size_t)(n0 + row) * D_MODEL + k0 + cl * 8, Bb + idx * 8);
        }
        __syncthreads();
        bf16x8 af[2], bfr[4];
#pragma unroll
        for (int i = 0; i < 2; i++) {
            int row = wm + i * 16 + lo16;
            af[i] = *(bf16x8*)(Ab + row * 32 + ((quad + row) & 3) * 8);
        }
#pragma unroll
        for (int j = 0; j < 4; j++) {
            int row = wn + j * 16 + lo16;
            bfr[j] = *(bf16x8*)(Bb + row * 32 + ((quad + row) & 3) * 8);
        }
#pragma unroll
        for (int i = 0; i < 2; i++)
#pragma unroll
            for (int j = 0; j < 4; j++)
                acc[i][j] = __builtin_amdgcn_mfma_f32_16x16x32_bf16(af[i], bfr[j], acc[i][j], 0, 0, 0);
    }

#pragma unroll
    for (int j = 0; j < 4; j++) {
        int col = n0 + wn + j * 16 + lo16;
        float bv2 = bias[col];
#pragma unroll
        for (int i = 0; i < 2; i++)
#pragma unroll
            for (int r = 0; r < 4; r++) {
                int m = m0 + wm + i * 16 + quad * 4 + r;
                out[(size_t)m * D_MODEL + col] = acc[i][j][r] + bv2;
            }
    }
}

// ---------------------------------------------------------------------------
extern "C" void kernel_launch(void* const* d_in, const int* in_sizes, int n_in,
                              void* d_out, int out_size, void* d_ws, size_t ws_size,
                              hipStream_t stream) {
    const float* q  = (const float*)d_in[0];
    const float* k  = (const float*)d_in[1];
    const float* v  = (const float*)d_in[2];
    const float* Wq = (const float*)d_in[3];
    const float* bq = (const float*)d_in[4];
    const float* Wk = (const float*)d_in[5];
    const float* bk = (const float*)d_in[6];
    const float* Wv = (const float*)d_in[7];
    const float* bv = (const float*)d_in[8];
    const float* Wo = (const float*)d_in[9];
    const float* bo = (const float*)d_in[10];
    float* out = (float*)d_out;

    // ws (bf16 elems): 4 weights (4M) + Qh/Kh/Vt (12M) + Op0/Op1 (8M) + L (fp32).
    bf16_t* Wqt = (bf16_t*)d_ws;
    bf16_t* Wkt = Wqt + (size_t)MEGA;
    bf16_t* Wvt = Wkt + (size_t)MEGA;
    bf16_t* Wot = Wvt + (size_t)MEGA;
    bf16_t* Qh  = Wot + (size_t)MEGA;                // [B,H,T,Hd]
    bf16_t* Kh  = Qh  + (size_t)M_ROWS * D_MODEL;
    bf16_t* Vt  = Kh  + (size_t)M_ROWS * D_MODEL;    // [B,H,Hd,T]
    bf16_t* Op0 = Vt  + (size_t)M_ROWS * D_MODEL;    // [B,T,D] partial (half 0)
    bf16_t* Op1 = Op0 + (size_t)M_ROWS * D_MODEL;    // [B,T,D] partial (half 1)
    float*  L0  = (float*)(Op1 + (size_t)M_ROWS * D_MODEL);  // [B*T*H]
    float*  L1  = L0 + (size_t)M_ROWS * NHEAD;

    prep<<<1024, 256, 0, stream>>>(Wq, Wk, Wv, Wo, Wqt, Wkt, Wvt, Wot);

    dim3 pg(M_ROWS / 128, 24);   // y: 0..7 Q, 8..15 K, 16..23 V
    proj_fused<<<pg, 256, 0, stream>>>(q, k, v, Wqt, Wkt, Wvt, bq, bk, bv, Qh, Kh, Vt);

    flash_attn<<<2048, 256, 0, stream>>>(Qh, Kh, Vt, Op0, Op1, L0, L1);

    dim3 og(M_ROWS / 64, D_MODEL / 128);
    out_gemm<<<og, 256, 0, stream>>>(Op0, Op1, L0, L1, Wot, bo, out);
}